// Round 2
// baseline (563.371 us; speedup 1.0000x reference)
//
#include <hip/hip_runtime.h>
#include <math.h>

// ---- geometry constants (match reference) ----
#define NA   24
#define NU   128
#define NV   64
#define NW   128   // volume W (x)
#define NH   128   // volume H (y)
#define ND   64    // volume D (z)
#define NS   128   // samples per ray
#define F_STEP 1.5625f            // 2*HS/S = 200/128
#define F_DL  (200.0f / 127.0f)   // linspace(156,356,128) spacing
#define F_L0  156.0f
#define INV_DL (127.0f / 200.0f)

#define NRAYS (NA * NV * NU)      // 196608
#define VOX   (NW * NH * ND)      // 1048576
#define NSEG  4

// padded volume: planes {guard, padz(-1), z0..z63, padz(64), guard} x 130 x 130
#define PPX  130
#define PPY  130
#define PPZ  68
#define PPLANE (PPX * PPY)        // 16900
#define PVN  (PPZ * PPLANE)       // 1,149,200
#define CBASE (2 * PPLANE + PPX + 1)   // voxel(0,0,0) linear offset

typedef float v2f __attribute__((ext_vector_type(2)));

// cos/sin(k*15 deg)
__device__ __constant__ float CSA[NA] = {
    1.0f,  0.96592582628906829f,  0.86602540378443865f,  0.70710678118654752f,
    0.5f,  0.25881904510252076f,  0.0f,                 -0.25881904510252076f,
   -0.5f, -0.70710678118654752f, -0.86602540378443865f, -0.96592582628906829f,
   -1.0f, -0.96592582628906829f, -0.86602540378443865f, -0.70710678118654752f,
   -0.5f, -0.25881904510252076f,  0.0f,                  0.25881904510252076f,
    0.5f,  0.70710678118654752f,  0.86602540378443865f,  0.96592582628906829f
};
__device__ __constant__ float SNA[NA] = {
    0.0f,  0.25881904510252076f,  0.5f,                  0.70710678118654752f,
    0.86602540378443865f,  0.96592582628906829f,  1.0f,  0.96592582628906829f,
    0.86602540378443865f,  0.70710678118654752f,  0.5f,  0.25881904510252076f,
    0.0f, -0.25881904510252076f, -0.5f,                 -0.70710678118654752f,
   -0.86602540378443865f, -0.96592582628906829f, -1.0f, -0.96592582628906829f,
   -0.86602540378443865f, -0.70710678118654752f, -0.5f, -0.25881904510252076f
};

// ---------------- volume padding: zero borders, copy interior ----------------
__global__ __launch_bounds__(256) void pad_kernel(const float* __restrict__ vol,
                                                  float* __restrict__ padv) {
    int i = blockIdx.x * 256 + threadIdx.x;
    if (i >= PVN) return;
    int x = i % PPX;
    int t = i / PPX;
    int y = t % PPY;
    int z = t / PPY;
    float val = 0.0f;
    if (z >= 2 && z <= 65 && y >= 1 && y <= 128 && x >= 1 && x <= 128)
        val = vol[(((z - 2) << 7) + (y - 1) << 7) + (x - 1)];
    padv[i] = val;
}

// Per-ray geometry for FP.
__device__ __forceinline__ void ray_setup(int a, int v, int u,
                                          float& sx, float& sy,
                                          float& dx, float& dy, float& dz) {
    float ang = (float)((double)a * (15.0 * M_PI / 180.0));
    float c = cosf(ang), s = sinf(ang);
    float uu = (float)u - 63.5f;
    float vv = (float)v - 31.5f;
    float ux = 512.0f * c - uu * s;
    float uy = 512.0f * s + uu * c;
    float uz = vv;
    float invn = 1.0f / sqrtf(ux * ux + uy * uy + uz * uz);
    dx = ux * invn; dy = uy * invn; dz = uz * invn;
    sx = -256.0f * c; sy = -256.0f * s;
}

// ---------------- forward projection, 4 ell-segments, padded-volume gather ----------------
__global__ __launch_bounds__(256) void fp_seg_kernel(const float* __restrict__ padv,
                                                     float* __restrict__ part) {
    int r = blockIdx.x * blockDim.x + threadIdx.x;
    int seg = blockIdx.y;
    int u = r & (NU - 1);
    int v = (r >> 7) & (NV - 1);
    int a = r >> 13;

    float sx, sy, dx, dy, dz;
    ray_setup(a, v, u, sx, sy, dx, dy, dz);

    // exact-support window (voxel weights are zero outside +-64.5 / +-32.5)
    float rx = 1.0f / dx, ry = 1.0f / dy, rz = 1.0f / dz;
    float ex0 = (-64.51f - sx) * rx, ex1 = (64.51f - sx) * rx;
    float ey0 = (-64.51f - sy) * ry, ey1 = (64.51f - sy) * ry;
    float ez0 = (-32.51f) * rz,      ez1 = (32.51f) * rz;
    float llo = fmaxf(fmaxf(fminf(ex0, ex1), fminf(ey0, ey1)), fminf(ez0, ez1));
    float lhi = fminf(fminf(fmaxf(ex0, ex1), fmaxf(ey0, ey1)), fmaxf(ez0, ez1));
    int i_lo = max(seg * 32,      (int)ceilf((llo - F_L0) * INV_DL));
    int i_hi = min(seg * 32 + 31, (int)floorf((lhi - F_L0) * INV_DL));

    float acc = 0.0f;
    for (int i = i_lo; i <= i_hi; ++i) {
        float ell = fmaf((float)i, F_DL, F_L0);
        float cx = fmaf(ell, dx, sx) + 63.5f;   // voxel-index space
        float cy = fmaf(ell, dy, sy) + 63.5f;
        float cz = ell * dz + 31.5f;
        float fx = floorf(cx), fy = floorf(cy), fz = floorf(cz);
        int ix = (int)fx, iy = (int)fy, iz = (int)fz;
        float wx1 = cx - fx, wy1 = cy - fy, wz1 = cz - fz;
        int base = iz * PPLANE + iy * PPX + ix + CBASE;
        const float* q0 = padv + base;
        const float* q1 = q0 + PPLANE;
        float v000 = q0[0],   v001 = q0[1];
        float v010 = q0[PPX], v011 = q0[PPX + 1];
        float v100 = q1[0],   v101 = q1[1];
        float v110 = q1[PPX], v111 = q1[PPX + 1];
        float c00 = fmaf(wx1, v001 - v000, v000);
        float c01 = fmaf(wx1, v011 - v010, v010);
        float c10 = fmaf(wx1, v101 - v100, v100);
        float c11 = fmaf(wx1, v111 - v110, v110);
        float c0  = fmaf(wy1, c01 - c00, c00);
        float c1  = fmaf(wy1, c11 - c10, c10);
        acc += fmaf(wz1, c1 - c0, c0);
    }
    part[seg * NRAYS + r] = acc;
}

// ------- residual + cw + Ram-Lak; writes TRANSPOSED resT[a][u][v] -------
__global__ __launch_bounds__(NU) void ramp_kernel(const float* __restrict__ part,
                                                  const float* __restrict__ p,
                                                  float* __restrict__ resT) {
    __shared__ float row[NU];
    int rowid = blockIdx.x;          // a*NV + v
    int u = threadIdx.x;
    int e = rowid * NU + u;
    int a = rowid >> 6;
    int v = rowid & (NV - 1);
    float sino = (part[e] + part[NRAYS + e] + part[2 * NRAYS + e] + part[3 * NRAYS + e]) * F_STEP;
    double du = (double)u - 64.0;
    double dv = (double)v - 32.0;
    float cw = (float)(512.0 / sqrt(262144.0 + dv * dv + du * du));
    row[u] = (sino - p[e]) * cw;
    __syncthreads();
    float acc = 0.125f * row[u];
#pragma unroll
    for (int d = 1; d <= 63; d += 2) {
        float f = (float)(-0.5 / (M_PI * M_PI * (double)(d * d)));
        float lo = (u - d >= 0) ? row[u - d] : 0.0f;
        float hi = (u + d < NU) ? row[u + d] : 0.0f;
        acc += f * (lo + hi);
    }
    resT[(a << 13) + (u << 6) + v] = acc;   // [a][u][v]
}

// ---------------- back projection: pipelined + wave-rotated angle order ----------------
// R17 structure: R16's cross-pair software pipeline (pair j+1 setup + first
// A/B column loads issued before pair j's k-loop) but at FULL occupancy:
// __launch_bounds__(256,8) -> waves-per-eu=8 -> 32 waves/CU allowed (R16's
// (256,4) capped residency at 16/CU: Occupancy 71->44%, +128us pure stall,
// VALU-busy TIME unchanged at ~161us). Pipeline state is 60 VGPR < 64 budget,
// so full occupancy costs nothing.
// NEW: per-wave angle-pair rotation (wave wv starts at pair 3*wv, wraps mod
// 12). Waves run identical-length code, so their setup/prefetch stalls are
// otherwise synchronized and TLP cannot interleave across them; rotating the
// start index puts each wave of a block in a different loop phase. Sum order
// into s_acc changes (atomicAdd, order-independent up to FP rounding).
// Angle indices stay wave-uniform via readfirstlane -> CSA/SNA remain s_loads.
// z-tent algebra: g in [-eps,1.25] => max(1-|g-2|,0) == max(g-1,0), sharing
// h1=g-1 with the AC1 weight (-3 VALU/body, <=1-ulp, exact 0 where val==0).
// Empty pairs run a 0-trip loop; us clamp keeps all reads inside ws.

#define DECL_ANG(P) \
    float P##_c, P##_sn, P##_tDL, P##_izbf; \
    int P##_ulo, P##_len, P##_us; \
    float P##_Ar, P##_Br;

#define COPY_ANG(D, S) do { \
    D##_c = S##_c; D##_sn = S##_sn; D##_tDL = S##_tDL; D##_izbf = S##_izbf; \
    D##_us = S##_us; D##_Ar = S##_Ar; D##_Br = S##_Br; \
} while (0)

#define SETUP_P(P, AIDX) do { \
    const float c_ = CSA[(AIDX)], s_ = SNA[(AIDX)]; \
    const float ab_ = fabsf(c_) + fabsf(s_); \
    const float rho_ = fmaf(x0, c_, fmaf(y0, s_, 256.0f)); \
    const float tvlo_ = (rho_ - ab_) * (1.0f / 512.0f); \
    const float yp_ = y0 * c_ - x0 * s_; \
    const float rl_ = __builtin_amdgcn_rcpf(rho_ - ab_); \
    const float rh_ = __builtin_amdgcn_rcpf(rho_ + ab_); \
    const float A_ = yp_ - ab_, B_ = yp_ + ab_; \
    const float um_ = 512.0f * A_ * ((A_ >= 0.0f) ? rh_ : rl_); \
    const float uM_ = 512.0f * B_ * ((B_ >= 0.0f) ? rl_ : rh_); \
    P##_ulo = max(0, (int)ceilf(um_ + 63.49f)); \
    P##_len = min(127, (int)floorf(uM_ + 63.51f)) - P##_ulo + 1; \
    const float zm_ = fmaf(vvf, (vvf >= 0.0f) ? (tvlo_ - 1.0e-3f) \
                                              : (tvlo_ + 7.2e-3f), 31.5f); \
    P##_izbf = floorf(zm_); \
    P##_tDL  = tvlo_ * INV_DL; \
    P##_c = c_; P##_sn = s_; \
} while (0)

#define PAIR_FINISH(P0, P1, TR) do { \
    TR = (max(max(P0##_len, P1##_len), 0) + 1) & ~1; \
    P0##_us = max(0, min(P0##_ulo, 128 - TR)); \
    P1##_us = max(0, min(P1##_ulo, 128 - TR)); \
} while (0)

#define ISSUE(P, AIDX) do { \
    const float* r_ = resT + ((AIDX) << 13) + (P##_us << 6) + lane; \
    P##_Ar = r_[0]; P##_Br = r_[64]; \
} while (0)

#define BP_BODY2(S, RV, UU) do {                                                 \
    const float pu = fmaf(-(UU), ksn##S, kc512##S);                              \
    const float qu = fmaf((UU), kc##S, ks512##S);                                \
    const float arg  = fmaf((UU), (UU), s2);                                     \
    const float invn = __builtin_amdgcn_rsqf(arg);                               \
    const float nn   = arg * invn;                                               \
    const float i0f  = ceilf(fmaf(ktDL##S, nn, cK));                             \
    const float ell0 = fmaf(i0f, F_DL, F_L0);                                    \
    v2f tp; tp.x = ell0 * invn; tp.y = fmaf(F_DL, invn, tp.x);                   \
    const v2f pu2 = {pu, pu}, qu2 = {qu, qu};                                    \
    v2f wx = __builtin_elementwise_max(                                          \
        one2 - __builtin_elementwise_abs(__builtin_elementwise_fma(tp, pu2, kmVx##S)), zero2); \
    v2f wy = __builtin_elementwise_max(                                          \
        one2 - __builtin_elementwise_abs(__builtin_elementwise_fma(tp, qu2, kmVy##S)), zero2); \
    v2f val = wx * wy * (v2f){(RV), (RV)};                                       \
    const v2f fz2 = __builtin_elementwise_fma(tp, vv2, h31);                     \
    const v2f g  = fz2 - kb0##S;                                                 \
    const v2f h1 = g - one2;                                                     \
    AC0##S = __builtin_elementwise_fma(__builtin_elementwise_max(                \
             one2 - __builtin_elementwise_abs(g), zero2), val, AC0##S);          \
    AC1##S = __builtin_elementwise_fma(__builtin_elementwise_max(                \
             one2 - __builtin_elementwise_abs(h1), zero2), val, AC1##S);         \
    AC2##S = __builtin_elementwise_fma(__builtin_elementwise_max(h1, zero2), val, AC2##S); \
} while (0)

__global__ __launch_bounds__(256, 8) void bp_gather16(const float* __restrict__ resT,
                                                      float* __restrict__ out) {
    __shared__ float s_acc[4 * 64];       // per-wave z-accumulator columns

    const int tid  = threadIdx.x;
    const int lane = tid & 63;            // = v
    const int wv   = tid >> 6;            // wave 0..3
    const int y    = blockIdx.x & 127;    // y-major
    const int xq   = blockIdx.x >> 7;     // 0..31
    const int xi   = xq * 4 + wv;         // 4 consecutive x per block

    const float x0 = (float)xi - 63.5f;
    const float y0 = (float)y  - 63.5f;
    const float vvf = (float)lane - 31.5f;
    const float s2  = fmaf(vvf, vvf, 262144.0f);   // vv^2 + 512^2
    const v2f vv2   = {vvf, vvf};
    const v2f one2  = {1.0f, 1.0f}, zero2 = {0.0f, 0.0f};
    const v2f h31   = {31.5f, 31.5f};
    const float cK  = -(F_L0 * INV_DL) - 1.0e-3f;

    s_acc[tid] = 0.0f;

    DECL_ANG(C0); DECL_ANG(C1); DECL_ANG(N0); DECL_ANG(N1);
    int cur_trips, nxt_trips;

    // per-wave rotated pair order: wave wv starts at pair 3*wv (wave-uniform)
    int pj = __builtin_amdgcn_readfirstlane(3 * (tid >> 6));

    // prologue: first pair setup + first-column loads (only cold start)
    {
        const int aP = __builtin_amdgcn_readfirstlane(2 * pj);
        SETUP_P(C0, aP); SETUP_P(C1, aP + 1);
        PAIR_FINISH(C0, C1, cur_trips);
        ISSUE(C0, aP); ISSUE(C1, aP + 1);
    }

    for (int j = 0; j < NA / 2; ++j) {
        const int a0 = __builtin_amdgcn_readfirstlane(2 * pj);
        const int a1 = a0 + 1;

        // ---- pipeline: set up the NEXT pair and issue its A/B loads NOW ----
        int nj = pj + 1; if (nj == NA / 2) nj = 0;     // last iter: dummy (wasted)
        const int aN = __builtin_amdgcn_readfirstlane(2 * nj);
        SETUP_P(N0, aN); SETUP_P(N1, aN + 1);
        PAIR_FINISH(N0, N1, nxt_trips);
        ISSUE(N0, aN); ISSUE(N1, aN + 1);

        // ---- k-loop over current pair's columns (regs prefetched last iter) ----
        const float kc0 = C0_c, ksn0 = C0_sn;
        const float kc1 = C1_c, ksn1 = C1_sn;
        const float kc5120 = 512.0f * kc0, ks5120 = 512.0f * ksn0;
        const float kc5121 = 512.0f * kc1, ks5121 = 512.0f * ksn1;
        const float mvx0 = fmaf(-256.0f, kc0, -x0);
        const float mvy0 = fmaf(-256.0f, ksn0, -y0);
        const float mvx1 = fmaf(-256.0f, kc1, -x0);
        const float mvy1 = fmaf(-256.0f, ksn1, -y0);
        const v2f kmVx0 = {mvx0, mvx0}, kmVy0 = {mvy0, mvy0};
        const v2f kmVx1 = {mvx1, mvx1}, kmVy1 = {mvy1, mvy1};
        const float ktDL0 = C0_tDL, ktDL1 = C1_tDL;
        const v2f kb00 = {C0_izbf, C0_izbf};
        const v2f kb01 = {C1_izbf, C1_izbf};

        v2f AC00 = zero2, AC10 = zero2, AC20 = zero2;
        v2f AC01 = zero2, AC11 = zero2, AC21 = zero2;

        const float* ru0 = resT + (a0 << 13) + (C0_us << 6) + lane;
        const float* ru1 = resT + (a1 << 13) + (C1_us << 6) + lane;
        float uu0 = (float)C0_us - 63.5f;
        float uu1 = (float)C1_us - 63.5f;

        float Ar0 = C0_Ar, Ar1 = C1_Ar;
        float Br0 = C0_Br, Br1 = C1_Br;
#pragma unroll 1
        for (int k = 0; k < cur_trips; k += 2) {
            const float Cr0 = ru0[128];
            const float Cr1 = ru1[128];
            const float Dr0 = ru0[192];
            const float Dr1 = ru1[192];
            BP_BODY2(0, Ar0, uu0);
            BP_BODY2(1, Ar1, uu1);
            BP_BODY2(0, Br0, uu0 + 1.0f);
            BP_BODY2(1, Br1, uu1 + 1.0f);
            Ar0 = Cr0; Ar1 = Cr1; Br0 = Dr0; Br1 = Dr1;
            ru0 += 128; ru1 += 128;
            uu0 += 2.0f; uu1 += 2.0f;
        }

        float* accw = s_acc + (wv << 6);      // wave-private column
        const int izb0 = (int)C0_izbf;
        const int izb1 = (int)C1_izbf;
        atomicAdd(&accw[izb0],     AC00.x + AC00.y);
        atomicAdd(&accw[izb0 + 1], AC10.x + AC10.y);
        atomicAdd(&accw[izb0 + 2], AC20.x + AC20.y);
        atomicAdd(&accw[izb1],     AC01.x + AC01.y);
        atomicAdd(&accw[izb1 + 1], AC11.x + AC11.y);
        atomicAdd(&accw[izb1 + 2], AC21.x + AC21.y);

        // ---- rotate pipeline state ----
        COPY_ANG(C0, N0); COPY_ANG(C1, N1);
        cur_trips = nxt_trips;
        pj = nj;
    }
    __syncthreads();

    // writeout: 4 consecutive x per 4 lanes -> 16B chunks
    const int z  = tid >> 2;
    const int w4 = tid & 3;
    out[(z << 14) + (y << 7) + xq * 4 + w4] = s_acc[(w4 << 6) + z] * F_STEP;
}

extern "C" void kernel_launch(void* const* d_in, const int* in_sizes, int n_in,
                              void* d_out, int out_size, void* d_ws, size_t ws_size,
                              hipStream_t stream) {
    const float* x = (const float*)d_in[0];   // [1,1,64,128,128]
    const float* p = (const float*)d_in[1];   // [1,1,24,64,128]
    float* out  = (float*)d_out;              // [1,1,64,128,128]
    float* resT = (float*)d_ws;               // transposed filtered residual, NRAYS floats
    float* part = resT + NRAYS;               // 4 FP segments, 4*NRAYS floats
    float* padv = part + NSEG * NRAYS;        // padded volume, PVN floats (~4.6 MB)

    pad_kernel<<<(PVN + 255) / 256, 256, 0, stream>>>(x, padv);
    dim3 fpg(NRAYS / 256, NSEG);
    fp_seg_kernel<<<fpg, 256, 0, stream>>>(padv, part);
    ramp_kernel<<<NA * NV, NU, 0, stream>>>(part, p, resT);
    bp_gather16<<<128 * 32, 256, 0, stream>>>(resT, out);
}

// Round 3
// 562.332 us; speedup vs baseline: 1.0018x; 1.0018x over previous
//
#include <hip/hip_runtime.h>
#include <math.h>

// ---- geometry constants (match reference) ----
#define NA   24
#define NU   128
#define NV   64
#define NW   128   // volume W (x)
#define NH   128   // volume H (y)
#define ND   64    // volume D (z)
#define NS   128   // samples per ray
#define F_STEP 1.5625f            // 2*HS/S = 200/128
#define F_DL  (200.0f / 127.0f)   // linspace(156,356,128) spacing
#define F_L0  156.0f
#define INV_DL (127.0f / 200.0f)

#define NRAYS (NA * NV * NU)      // 196608
#define VOX   (NW * NH * ND)      // 1048576
#define NSEG  4

// padded volume: planes {guard, padz(-1), z0..z63, padz(64), guard} x 130 x 130
#define PPX  130
#define PPY  130
#define PPZ  68
#define PPLANE (PPX * PPY)        // 16900
#define PVN  (PPZ * PPLANE)       // 1,149,200
#define CBASE (2 * PPLANE + PPX + 1)   // voxel(0,0,0) linear offset

typedef float v2f __attribute__((ext_vector_type(2)));

// cos/sin(k*15 deg)
__device__ __constant__ float CSA[NA] = {
    1.0f,  0.96592582628906829f,  0.86602540378443865f,  0.70710678118654752f,
    0.5f,  0.25881904510252076f,  0.0f,                 -0.25881904510252076f,
   -0.5f, -0.70710678118654752f, -0.86602540378443865f, -0.96592582628906829f,
   -1.0f, -0.96592582628906829f, -0.86602540378443865f, -0.70710678118654752f,
   -0.5f, -0.25881904510252076f,  0.0f,                  0.25881904510252076f,
    0.5f,  0.70710678118654752f,  0.86602540378443865f,  0.96592582628906829f
};
__device__ __constant__ float SNA[NA] = {
    0.0f,  0.25881904510252076f,  0.5f,                  0.70710678118654752f,
    0.86602540378443865f,  0.96592582628906829f,  1.0f,  0.96592582628906829f,
    0.86602540378443865f,  0.70710678118654752f,  0.5f,  0.25881904510252076f,
    0.0f, -0.25881904510252076f, -0.5f,                 -0.70710678118654752f,
   -0.86602540378443865f, -0.96592582628906829f, -1.0f, -0.96592582628906829f,
   -0.86602540378443865f, -0.70710678118654752f, -0.5f, -0.25881904510252076f
};

// ---------------- volume padding: zero borders, copy interior ----------------
__global__ __launch_bounds__(256) void pad_kernel(const float* __restrict__ vol,
                                                  float* __restrict__ padv) {
    int i = blockIdx.x * 256 + threadIdx.x;
    if (i >= PVN) return;
    int x = i % PPX;
    int t = i / PPX;
    int y = t % PPY;
    int z = t / PPY;
    float val = 0.0f;
    if (z >= 2 && z <= 65 && y >= 1 && y <= 128 && x >= 1 && x <= 128)
        val = vol[(((z - 2) << 7) + (y - 1) << 7) + (x - 1)];
    padv[i] = val;
}

// Per-ray geometry for FP.
__device__ __forceinline__ void ray_setup(int a, int v, int u,
                                          float& sx, float& sy,
                                          float& dx, float& dy, float& dz) {
    float ang = (float)((double)a * (15.0 * M_PI / 180.0));
    float c = cosf(ang), s = sinf(ang);
    float uu = (float)u - 63.5f;
    float vv = (float)v - 31.5f;
    float ux = 512.0f * c - uu * s;
    float uy = 512.0f * s + uu * c;
    float uz = vv;
    float invn = 1.0f / sqrtf(ux * ux + uy * uy + uz * uz);
    dx = ux * invn; dy = uy * invn; dz = uz * invn;
    sx = -256.0f * c; sy = -256.0f * s;
}

// ---------------- forward projection, 4 ell-segments, padded-volume gather ----------------
__global__ __launch_bounds__(256) void fp_seg_kernel(const float* __restrict__ padv,
                                                     float* __restrict__ part) {
    int r = blockIdx.x * blockDim.x + threadIdx.x;
    int seg = blockIdx.y;
    int u = r & (NU - 1);
    int v = (r >> 7) & (NV - 1);
    int a = r >> 13;

    float sx, sy, dx, dy, dz;
    ray_setup(a, v, u, sx, sy, dx, dy, dz);

    // exact-support window (voxel weights are zero outside +-64.5 / +-32.5)
    float rx = 1.0f / dx, ry = 1.0f / dy, rz = 1.0f / dz;
    float ex0 = (-64.51f - sx) * rx, ex1 = (64.51f - sx) * rx;
    float ey0 = (-64.51f - sy) * ry, ey1 = (64.51f - sy) * ry;
    float ez0 = (-32.51f) * rz,      ez1 = (32.51f) * rz;
    float llo = fmaxf(fmaxf(fminf(ex0, ex1), fminf(ey0, ey1)), fminf(ez0, ez1));
    float lhi = fminf(fminf(fmaxf(ex0, ex1), fmaxf(ey0, ey1)), fmaxf(ez0, ez1));
    int i_lo = max(seg * 32,      (int)ceilf((llo - F_L0) * INV_DL));
    int i_hi = min(seg * 32 + 31, (int)floorf((lhi - F_L0) * INV_DL));

    float acc = 0.0f;
    for (int i = i_lo; i <= i_hi; ++i) {
        float ell = fmaf((float)i, F_DL, F_L0);
        float cx = fmaf(ell, dx, sx) + 63.5f;   // voxel-index space
        float cy = fmaf(ell, dy, sy) + 63.5f;
        float cz = ell * dz + 31.5f;
        float fx = floorf(cx), fy = floorf(cy), fz = floorf(cz);
        int ix = (int)fx, iy = (int)fy, iz = (int)fz;
        float wx1 = cx - fx, wy1 = cy - fy, wz1 = cz - fz;
        int base = iz * PPLANE + iy * PPX + ix + CBASE;
        const float* q0 = padv + base;
        const float* q1 = q0 + PPLANE;
        float v000 = q0[0],   v001 = q0[1];
        float v010 = q0[PPX], v011 = q0[PPX + 1];
        float v100 = q1[0],   v101 = q1[1];
        float v110 = q1[PPX], v111 = q1[PPX + 1];
        float c00 = fmaf(wx1, v001 - v000, v000);
        float c01 = fmaf(wx1, v011 - v010, v010);
        float c10 = fmaf(wx1, v101 - v100, v100);
        float c11 = fmaf(wx1, v111 - v110, v110);
        float c0  = fmaf(wy1, c01 - c00, c00);
        float c1  = fmaf(wy1, c11 - c10, c10);
        acc += fmaf(wz1, c1 - c0, c0);
    }
    part[seg * NRAYS + r] = acc;
}

// ------- residual + cw + Ram-Lak; writes TRANSPOSED resT[a][u][v] -------
__global__ __launch_bounds__(NU) void ramp_kernel(const float* __restrict__ part,
                                                  const float* __restrict__ p,
                                                  float* __restrict__ resT) {
    __shared__ float row[NU];
    int rowid = blockIdx.x;          // a*NV + v
    int u = threadIdx.x;
    int e = rowid * NU + u;
    int a = rowid >> 6;
    int v = rowid & (NV - 1);
    float sino = (part[e] + part[NRAYS + e] + part[2 * NRAYS + e] + part[3 * NRAYS + e]) * F_STEP;
    double du = (double)u - 64.0;
    double dv = (double)v - 32.0;
    float cw = (float)(512.0 / sqrt(262144.0 + dv * dv + du * du));
    row[u] = (sino - p[e]) * cw;
    __syncthreads();
    float acc = 0.125f * row[u];
#pragma unroll
    for (int d = 1; d <= 63; d += 2) {
        float f = (float)(-0.5 / (M_PI * M_PI * (double)(d * d)));
        float lo = (u - d >= 0) ? row[u - d] : 0.0f;
        float hi = (u + d < NU) ? row[u + d] : 0.0f;
        acc += f * (lo + hi);
    }
    resT[(a << 13) + (u << 6) + v] = acc;   // [a][u][v]
}

// ---------------- back projection: pipelined + rotated, unconstrained alloc ----------------
// R18. Evidence so far: VALU-busy TIME is invariant (~160us) across R0/R1/R2;
// everything above it is stall. Two failed flag settings:
//   (256,8): allocator caps at 32 arch-VGPRs -> pipeline state spills
//            (WRITE_SIZE 6->154 MB scratch), 465us.
//   (256,4): no spill (60 VGPR) but residency ~14 waves/CU, 463us.
// R18 removes the waves hint: HW occupancy follows ACTUAL vgpr count
// (steps at 64/128/256), so any allocation <=64 still permits 8 waves/SIMD.
// To stay safely under 64: izbf is no longer double-buffered -- recomputed at
// k-loop entry from carried wave-uniform tvlo (3 VALU/angle, bitwise-identical
// math). Carried per-lane pipeline state = Ar/Br x2 angles only (4 VGPR).
// Keeps: cross-pair setup+load prefetch, per-wave angle-pair rotation
// (decorrelates wave phases so TLP can interleave stalls), z-tent via
// shared h1=g-1, wave-uniform angle indices via readfirstlane.

#define DECL_ANG(P) \
    float P##_c, P##_sn, P##_tvlo; \
    int P##_ulo, P##_len, P##_us; \
    float P##_Ar, P##_Br;

#define COPY_ANG(D, S) do { \
    D##_c = S##_c; D##_sn = S##_sn; D##_tvlo = S##_tvlo; \
    D##_us = S##_us; D##_Ar = S##_Ar; D##_Br = S##_Br; \
} while (0)

#define SETUP_P(P, AIDX) do { \
    const float c_ = CSA[(AIDX)], s_ = SNA[(AIDX)]; \
    const float ab_ = fabsf(c_) + fabsf(s_); \
    const float rho_ = fmaf(x0, c_, fmaf(y0, s_, 256.0f)); \
    const float yp_ = y0 * c_ - x0 * s_; \
    const float rl_ = __builtin_amdgcn_rcpf(rho_ - ab_); \
    const float rh_ = __builtin_amdgcn_rcpf(rho_ + ab_); \
    const float A_ = yp_ - ab_, B_ = yp_ + ab_; \
    const float um_ = 512.0f * A_ * ((A_ >= 0.0f) ? rh_ : rl_); \
    const float uM_ = 512.0f * B_ * ((B_ >= 0.0f) ? rl_ : rh_); \
    P##_ulo = max(0, (int)ceilf(um_ + 63.49f)); \
    P##_len = min(127, (int)floorf(uM_ + 63.51f)) - P##_ulo + 1; \
    P##_tvlo = (rho_ - ab_) * (1.0f / 512.0f); \
    P##_c = c_; P##_sn = s_; \
} while (0)

#define PAIR_FINISH(P0, P1, TR) do { \
    TR = (max(max(P0##_len, P1##_len), 0) + 1) & ~1; \
    P0##_us = max(0, min(P0##_ulo, 128 - TR)); \
    P1##_us = max(0, min(P1##_ulo, 128 - TR)); \
} while (0)

#define ISSUE(P, AIDX) do { \
    const float* r_ = resT + ((AIDX) << 13) + (P##_us << 6) + lane; \
    P##_Ar = r_[0]; P##_Br = r_[64]; \
} while (0)

#define BP_BODY2(S, RV, UU) do {                                                 \
    const float pu = fmaf(-(UU), ksn##S, kc512##S);                              \
    const float qu = fmaf((UU), kc##S, ks512##S);                                \
    const float arg  = fmaf((UU), (UU), s2);                                     \
    const float invn = __builtin_amdgcn_rsqf(arg);                               \
    const float nn   = arg * invn;                                               \
    const float i0f  = ceilf(fmaf(ktDL##S, nn, cK));                             \
    const float ell0 = fmaf(i0f, F_DL, F_L0);                                    \
    v2f tp; tp.x = ell0 * invn; tp.y = fmaf(F_DL, invn, tp.x);                   \
    const v2f pu2 = {pu, pu}, qu2 = {qu, qu};                                    \
    v2f wx = __builtin_elementwise_max(                                          \
        one2 - __builtin_elementwise_abs(__builtin_elementwise_fma(tp, pu2, kmVx##S)), zero2); \
    v2f wy = __builtin_elementwise_max(                                          \
        one2 - __builtin_elementwise_abs(__builtin_elementwise_fma(tp, qu2, kmVy##S)), zero2); \
    v2f val = wx * wy * (v2f){(RV), (RV)};                                       \
    const v2f fz2 = __builtin_elementwise_fma(tp, vv2, h31);                     \
    const v2f g  = fz2 - kb0##S;                                                 \
    const v2f h1 = g - one2;                                                     \
    AC0##S = __builtin_elementwise_fma(__builtin_elementwise_max(                \
             one2 - __builtin_elementwise_abs(g), zero2), val, AC0##S);          \
    AC1##S = __builtin_elementwise_fma(__builtin_elementwise_max(                \
             one2 - __builtin_elementwise_abs(h1), zero2), val, AC1##S);         \
    AC2##S = __builtin_elementwise_fma(__builtin_elementwise_max(h1, zero2), val, AC2##S); \
} while (0)

__global__ __launch_bounds__(256) void bp_gather17(const float* __restrict__ resT,
                                                   float* __restrict__ out) {
    __shared__ float s_acc[4 * 64];       // per-wave z-accumulator columns

    const int tid  = threadIdx.x;
    const int lane = tid & 63;            // = v
    const int wv   = tid >> 6;            // wave 0..3
    const int y    = blockIdx.x & 127;    // y-major
    const int xq   = blockIdx.x >> 7;     // 0..31
    const int xi   = xq * 4 + wv;         // 4 consecutive x per block

    const float x0 = (float)xi - 63.5f;
    const float y0 = (float)y  - 63.5f;
    const float vvf = (float)lane - 31.5f;
    const float s2  = fmaf(vvf, vvf, 262144.0f);   // vv^2 + 512^2
    const v2f vv2   = {vvf, vvf};
    const v2f one2  = {1.0f, 1.0f}, zero2 = {0.0f, 0.0f};
    const v2f h31   = {31.5f, 31.5f};
    const float cK  = -(F_L0 * INV_DL) - 1.0e-3f;

    s_acc[tid] = 0.0f;

    DECL_ANG(C0); DECL_ANG(C1); DECL_ANG(N0); DECL_ANG(N1);
    int cur_trips, nxt_trips;

    // per-wave rotated pair order: wave wv starts at pair 3*wv (wave-uniform)
    int pj = __builtin_amdgcn_readfirstlane(3 * (tid >> 6));

    // prologue: first pair setup + first-column loads (only cold start)
    {
        const int aP = __builtin_amdgcn_readfirstlane(2 * pj);
        SETUP_P(C0, aP); SETUP_P(C1, aP + 1);
        PAIR_FINISH(C0, C1, cur_trips);
        ISSUE(C0, aP); ISSUE(C1, aP + 1);
    }

    for (int j = 0; j < NA / 2; ++j) {
        const int a0 = __builtin_amdgcn_readfirstlane(2 * pj);
        const int a1 = a0 + 1;

        // ---- pipeline: set up the NEXT pair and issue its A/B loads NOW ----
        int nj = pj + 1; if (nj == NA / 2) nj = 0;     // last iter: dummy (wasted)
        const int aN = __builtin_amdgcn_readfirstlane(2 * nj);
        SETUP_P(N0, aN); SETUP_P(N1, aN + 1);
        PAIR_FINISH(N0, N1, nxt_trips);
        ISSUE(N0, aN); ISSUE(N1, aN + 1);

        // ---- k-loop constants for current pair (izbf recomputed here, not carried) ----
        const float kc0 = C0_c, ksn0 = C0_sn;
        const float kc1 = C1_c, ksn1 = C1_sn;
        const float kc5120 = 512.0f * kc0, ks5120 = 512.0f * ksn0;
        const float kc5121 = 512.0f * kc1, ks5121 = 512.0f * ksn1;
        const float mvx0 = fmaf(-256.0f, kc0, -x0);
        const float mvy0 = fmaf(-256.0f, ksn0, -y0);
        const float mvx1 = fmaf(-256.0f, kc1, -x0);
        const float mvy1 = fmaf(-256.0f, ksn1, -y0);
        const v2f kmVx0 = {mvx0, mvx0}, kmVy0 = {mvy0, mvy0};
        const v2f kmVx1 = {mvx1, mvx1}, kmVy1 = {mvy1, mvy1};
        const float ktDL0 = C0_tvlo * INV_DL;
        const float ktDL1 = C1_tvlo * INV_DL;
        // z-base recompute (bitwise-identical to the old SETUP-time version)
        const float tvs0 = (vvf >= 0.0f) ? (C0_tvlo - 1.0e-3f) : (C0_tvlo + 7.2e-3f);
        const float tvs1 = (vvf >= 0.0f) ? (C1_tvlo - 1.0e-3f) : (C1_tvlo + 7.2e-3f);
        const float izbf0 = floorf(fmaf(vvf, tvs0, 31.5f));
        const float izbf1 = floorf(fmaf(vvf, tvs1, 31.5f));
        const v2f kb00 = {izbf0, izbf0};
        const v2f kb01 = {izbf1, izbf1};

        v2f AC00 = zero2, AC10 = zero2, AC20 = zero2;
        v2f AC01 = zero2, AC11 = zero2, AC21 = zero2;

        const float* ru0 = resT + (a0 << 13) + (C0_us << 6) + lane;
        const float* ru1 = resT + (a1 << 13) + (C1_us << 6) + lane;
        float uu0 = (float)C0_us - 63.5f;
        float uu1 = (float)C1_us - 63.5f;

        float Ar0 = C0_Ar, Ar1 = C1_Ar;
        float Br0 = C0_Br, Br1 = C1_Br;
#pragma unroll 1
        for (int k = 0; k < cur_trips; k += 2) {
            const float Cr0 = ru0[128];
            const float Cr1 = ru1[128];
            const float Dr0 = ru0[192];
            const float Dr1 = ru1[192];
            BP_BODY2(0, Ar0, uu0);
            BP_BODY2(1, Ar1, uu1);
            BP_BODY2(0, Br0, uu0 + 1.0f);
            BP_BODY2(1, Br1, uu1 + 1.0f);
            Ar0 = Cr0; Ar1 = Cr1; Br0 = Dr0; Br1 = Dr1;
            ru0 += 128; ru1 += 128;
            uu0 += 2.0f; uu1 += 2.0f;
        }

        float* accw = s_acc + (wv << 6);      // wave-private column
        const int izb0 = (int)izbf0;
        const int izb1 = (int)izbf1;
        atomicAdd(&accw[izb0],     AC00.x + AC00.y);
        atomicAdd(&accw[izb0 + 1], AC10.x + AC10.y);
        atomicAdd(&accw[izb0 + 2], AC20.x + AC20.y);
        atomicAdd(&accw[izb1],     AC01.x + AC01.y);
        atomicAdd(&accw[izb1 + 1], AC11.x + AC11.y);
        atomicAdd(&accw[izb1 + 2], AC21.x + AC21.y);

        // ---- rotate pipeline state ----
        COPY_ANG(C0, N0); COPY_ANG(C1, N1);
        cur_trips = nxt_trips;
        pj = nj;
    }
    __syncthreads();

    // writeout: 4 consecutive x per 4 lanes -> 16B chunks
    const int z  = tid >> 2;
    const int w4 = tid & 3;
    out[(z << 14) + (y << 7) + xq * 4 + w4] = s_acc[(w4 << 6) + z] * F_STEP;
}

extern "C" void kernel_launch(void* const* d_in, const int* in_sizes, int n_in,
                              void* d_out, int out_size, void* d_ws, size_t ws_size,
                              hipStream_t stream) {
    const float* x = (const float*)d_in[0];   // [1,1,64,128,128]
    const float* p = (const float*)d_in[1];   // [1,1,24,64,128]
    float* out  = (float*)d_out;              // [1,1,64,128,128]
    float* resT = (float*)d_ws;               // transposed filtered residual, NRAYS floats
    float* part = resT + NRAYS;               // 4 FP segments, 4*NRAYS floats
    float* padv = part + NSEG * NRAYS;        // padded volume, PVN floats (~4.6 MB)

    pad_kernel<<<(PVN + 255) / 256, 256, 0, stream>>>(x, padv);
    dim3 fpg(NRAYS / 256, NSEG);
    fp_seg_kernel<<<fpg, 256, 0, stream>>>(padv, part);
    ramp_kernel<<<NA * NV, NU, 0, stream>>>(part, p, resT);
    bp_gather17<<<128 * 32, 256, 0, stream>>>(resT, out);
}

// Round 4
// 430.604 us; speedup vs baseline: 1.3083x; 1.3059x over previous
//
#include <hip/hip_runtime.h>
#include <math.h>

// ---- geometry constants (match reference) ----
#define NA   24
#define NU   128
#define NV   64
#define NW   128   // volume W (x)
#define NH   128   // volume H (y)
#define ND   64    // volume D (z)
#define NS   128   // samples per ray
#define F_STEP 1.5625f            // 2*HS/S = 200/128
#define F_DL  (200.0f / 127.0f)   // linspace(156,356,128) spacing
#define F_L0  156.0f
#define INV_DL (127.0f / 200.0f)

#define NRAYS (NA * NV * NU)      // 196608
#define VOX   (NW * NH * ND)      // 1048576
#define NSEG  4

// padded volume: planes {guard, padz(-1), z0..z63, padz(64), guard} x 130 x 130
#define PPX  130
#define PPY  130
#define PPZ  68
#define PPLANE (PPX * PPY)        // 16900
#define PVN  (PPZ * PPLANE)       // 1,149,200
#define CBASE (2 * PPLANE + PPX + 1)   // voxel(0,0,0) linear offset

typedef float v2f __attribute__((ext_vector_type(2)));

// cos/sin(k*15 deg)
__device__ __constant__ float CSA[NA] = {
    1.0f,  0.96592582628906829f,  0.86602540378443865f,  0.70710678118654752f,
    0.5f,  0.25881904510252076f,  0.0f,                 -0.25881904510252076f,
   -0.5f, -0.70710678118654752f, -0.86602540378443865f, -0.96592582628906829f,
   -1.0f, -0.96592582628906829f, -0.86602540378443865f, -0.70710678118654752f,
   -0.5f, -0.25881904510252076f,  0.0f,                  0.25881904510252076f,
    0.5f,  0.70710678118654752f,  0.86602540378443865f,  0.96592582628906829f
};
__device__ __constant__ float SNA[NA] = {
    0.0f,  0.25881904510252076f,  0.5f,                  0.70710678118654752f,
    0.86602540378443865f,  0.96592582628906829f,  1.0f,  0.96592582628906829f,
    0.86602540378443865f,  0.70710678118654752f,  0.5f,  0.25881904510252076f,
    0.0f, -0.25881904510252076f, -0.5f,                 -0.70710678118654752f,
   -0.86602540378443865f, -0.96592582628906829f, -1.0f, -0.96592582628906829f,
   -0.86602540378443865f, -0.70710678118654752f, -0.5f, -0.25881904510252076f
};

// ---------------- volume padding: zero borders, copy interior ----------------
__global__ __launch_bounds__(256) void pad_kernel(const float* __restrict__ vol,
                                                  float* __restrict__ padv) {
    int i = blockIdx.x * 256 + threadIdx.x;
    if (i >= PVN) return;
    int x = i % PPX;
    int t = i / PPX;
    int y = t % PPY;
    int z = t / PPY;
    float val = 0.0f;
    if (z >= 2 && z <= 65 && y >= 1 && y <= 128 && x >= 1 && x <= 128)
        val = vol[(((z - 2) << 7) + (y - 1) << 7) + (x - 1)];
    padv[i] = val;
}

// Per-ray geometry for FP.
__device__ __forceinline__ void ray_setup(int a, int v, int u,
                                          float& sx, float& sy,
                                          float& dx, float& dy, float& dz) {
    float ang = (float)((double)a * (15.0 * M_PI / 180.0));
    float c = cosf(ang), s = sinf(ang);
    float uu = (float)u - 63.5f;
    float vv = (float)v - 31.5f;
    float ux = 512.0f * c - uu * s;
    float uy = 512.0f * s + uu * c;
    float uz = vv;
    float invn = 1.0f / sqrtf(ux * ux + uy * uy + uz * uz);
    dx = ux * invn; dy = uy * invn; dz = uz * invn;
    sx = -256.0f * c; sy = -256.0f * s;
}

// ---------------- forward projection, 4 ell-segments, padded-volume gather ----------------
__global__ __launch_bounds__(256) void fp_seg_kernel(const float* __restrict__ padv,
                                                     float* __restrict__ part) {
    int r = blockIdx.x * blockDim.x + threadIdx.x;
    int seg = blockIdx.y;
    int u = r & (NU - 1);
    int v = (r >> 7) & (NV - 1);
    int a = r >> 13;

    float sx, sy, dx, dy, dz;
    ray_setup(a, v, u, sx, sy, dx, dy, dz);

    // exact-support window (voxel weights are zero outside +-64.5 / +-32.5)
    float rx = 1.0f / dx, ry = 1.0f / dy, rz = 1.0f / dz;
    float ex0 = (-64.51f - sx) * rx, ex1 = (64.51f - sx) * rx;
    float ey0 = (-64.51f - sy) * ry, ey1 = (64.51f - sy) * ry;
    float ez0 = (-32.51f) * rz,      ez1 = (32.51f) * rz;
    float llo = fmaxf(fmaxf(fminf(ex0, ex1), fminf(ey0, ey1)), fminf(ez0, ez1));
    float lhi = fminf(fminf(fmaxf(ex0, ex1), fmaxf(ey0, ey1)), fmaxf(ez0, ez1));
    int i_lo = max(seg * 32,      (int)ceilf((llo - F_L0) * INV_DL));
    int i_hi = min(seg * 32 + 31, (int)floorf((lhi - F_L0) * INV_DL));

    float acc = 0.0f;
    for (int i = i_lo; i <= i_hi; ++i) {
        float ell = fmaf((float)i, F_DL, F_L0);
        float cx = fmaf(ell, dx, sx) + 63.5f;   // voxel-index space
        float cy = fmaf(ell, dy, sy) + 63.5f;
        float cz = ell * dz + 31.5f;
        float fx = floorf(cx), fy = floorf(cy), fz = floorf(cz);
        int ix = (int)fx, iy = (int)fy, iz = (int)fz;
        float wx1 = cx - fx, wy1 = cy - fy, wz1 = cz - fz;
        int base = iz * PPLANE + iy * PPX + ix + CBASE;
        const float* q0 = padv + base;
        const float* q1 = q0 + PPLANE;
        float v000 = q0[0],   v001 = q0[1];
        float v010 = q0[PPX], v011 = q0[PPX + 1];
        float v100 = q1[0],   v101 = q1[1];
        float v110 = q1[PPX], v111 = q1[PPX + 1];
        float c00 = fmaf(wx1, v001 - v000, v000);
        float c01 = fmaf(wx1, v011 - v010, v010);
        float c10 = fmaf(wx1, v101 - v100, v100);
        float c11 = fmaf(wx1, v111 - v110, v110);
        float c0  = fmaf(wy1, c01 - c00, c00);
        float c1  = fmaf(wy1, c11 - c10, c10);
        acc += fmaf(wz1, c1 - c0, c0);
    }
    part[seg * NRAYS + r] = acc;
}

// ------- residual + cw + Ram-Lak; writes TRANSPOSED resT[a][u][v] -------
__global__ __launch_bounds__(NU) void ramp_kernel(const float* __restrict__ part,
                                                  const float* __restrict__ p,
                                                  float* __restrict__ resT) {
    __shared__ float row[NU];
    int rowid = blockIdx.x;          // a*NV + v
    int u = threadIdx.x;
    int e = rowid * NU + u;
    int a = rowid >> 6;
    int v = rowid & (NV - 1);
    float sino = (part[e] + part[NRAYS + e] + part[2 * NRAYS + e] + part[3 * NRAYS + e]) * F_STEP;
    double du = (double)u - 64.0;
    double dv = (double)v - 32.0;
    float cw = (float)(512.0 / sqrt(262144.0 + dv * dv + du * du));
    row[u] = (sino - p[e]) * cw;
    __syncthreads();
    float acc = 0.125f * row[u];
#pragma unroll
    for (int d = 1; d <= 63; d += 2) {
        float f = (float)(-0.5 / (M_PI * M_PI * (double)(d * d)));
        float lo = (u - d >= 0) ? row[u - d] : 0.0f;
        float hi = (u + d < NU) ? row[u + d] : 0.0f;
        acc += f * (lo + hi);
    }
    resT[(a << 13) + (u << 6) + v] = acc;   // [a][u][v]
}

// ---------------- back projection: R0 structure + wave-rotated pair order ----------------
// R19. Evidence synthesis (R0..R3):
//  * VGPR pool is ~256/lane-slot: 32 regs -> 8 waves/SIMD (occ 71%), 60 regs
//    -> 4 waves (occ 44%). Any carried state above 32 VGPRs loses occupancy,
//    and cross-pair prefetch never paid for it (per-wave life invariant 119us).
//  * VALU-busy TIME ~161us constant = the work; each wave is ~91% stalled.
//    Setup-latency and plain L2 latency are ruled out (prefetching them across
//    pairs changed nothing; request rates are tiny).
//  * Untested at full occupancy: LOCKSTEP CORRELATION. All ~23 resident
//    waves/CU run identical code launched simultaneously -> their per-pair
//    bursts (SETUP scalar loads, 6 LDS atomics, vmcnt drains) collide at the
//    same instants; no phase diversity for the scheduler to fill stalls.
// R19 = EXACT R0 kernel (32-VGPR body, (256,8), 2-col prefetch, shared trips)
// + per-wave angle-pair rotation: wave wv starts at pair 3*wv, wraps mod 12.
// Rotation index is wave-uniform (readfirstlane -> SGPR), so VGPR stays 32.
// Sum order into s_acc changes only via atomic ordering (rounding-level).
// Also kept: h1 z-tent form (g in [-eps,1.25] => max(1-|g-2|,0)==max(g-1,0)),
// bitwise-validated in R1/R3, -3 VALU/body.

#define SETUP_ANGLE(S, AIDX, AB)                                                 \
    const float c##S = CSA[AIDX], sn##S = SNA[AIDX];                             \
    const float c512##S = 512.0f * c##S;                                         \
    const float s512##S = 512.0f * sn##S;                                        \
    const float rho##S = fmaf(x0, c##S, fmaf(y0, sn##S, 256.0f));                \
    const float Vx##S = x0 + 256.0f * c##S;                                      \
    const float Vy##S = y0 + 256.0f * sn##S;                                     \
    const float tvlo##S = (rho##S - (AB)) * (1.0f / 512.0f);                     \
    const float yp##S = y0 * c##S - x0 * sn##S;                                  \
    const float rl##S = __builtin_amdgcn_rcpf(rho##S - (AB));                    \
    const float rh##S = __builtin_amdgcn_rcpf(rho##S + (AB));                    \
    const float A##S = yp##S - (AB), B##S = yp##S + (AB);                        \
    const float um##S = 512.0f * A##S * ((A##S >= 0.0f) ? rh##S : rl##S);        \
    const float uM##S = 512.0f * B##S * ((B##S >= 0.0f) ? rl##S : rh##S);        \
    const int u_lo##S = max(0,   (int)ceilf(um##S + 63.49f));                    \
    const int u_hi##S = min(127, (int)floorf(uM##S + 63.51f));                   \
    const int len##S = max(0, u_hi##S - u_lo##S + 1);                            \
    const float Zmin##S = fmaf(vvf, (vvf >= 0.0f) ? (tvlo##S - 1.0e-3f)          \
                                                  : (tvlo##S + 7.2e-3f), 31.5f); \
    const float izbf##S = floorf(Zmin##S);                                       \
    const int   izb##S  = (int)izbf##S;                                          \
    const v2f b0##S = {izbf##S, izbf##S};                                        \
    const float tDL##S = tvlo##S * INV_DL;                                       \
    const v2f mVx##S = {-Vx##S, -Vx##S}, mVy##S = {-Vy##S, -Vy##S};

#define BP_BODY2(S, RV, UU) do {                                                 \
    const float pu = fmaf(-(UU), sn##S, c512##S);                                \
    const float qu = fmaf((UU), c##S, s512##S);                                  \
    const float arg  = fmaf((UU), (UU), s2);                                     \
    const float invn = __builtin_amdgcn_rsqf(arg);                               \
    const float nn   = arg * invn;                                               \
    const float i0f  = ceilf(fmaf(tDL##S, nn, cK));                              \
    const float ell0 = fmaf(i0f, F_DL, F_L0);                                    \
    v2f tp; tp.x = ell0 * invn; tp.y = fmaf(F_DL, invn, tp.x);                   \
    const v2f pu2 = {pu, pu}, qu2 = {qu, qu};                                    \
    v2f wx = __builtin_elementwise_max(                                          \
        one2 - __builtin_elementwise_abs(__builtin_elementwise_fma(tp, pu2, mVx##S)), zero2); \
    v2f wy = __builtin_elementwise_max(                                          \
        one2 - __builtin_elementwise_abs(__builtin_elementwise_fma(tp, qu2, mVy##S)), zero2); \
    v2f val = wx * wy * (v2f){(RV), (RV)};                                       \
    const v2f fz2 = __builtin_elementwise_fma(tp, vv2, h31);                     \
    const v2f g  = fz2 - b0##S;                                                  \
    const v2f h1 = g - one2;                                                     \
    AC0##S = __builtin_elementwise_fma(__builtin_elementwise_max(                \
             one2 - __builtin_elementwise_abs(g), zero2), val, AC0##S);          \
    AC1##S = __builtin_elementwise_fma(__builtin_elementwise_max(                \
             one2 - __builtin_elementwise_abs(h1), zero2), val, AC1##S);         \
    AC2##S = __builtin_elementwise_fma(__builtin_elementwise_max(h1, zero2), val, AC2##S); \
} while (0)

__global__ __launch_bounds__(256, 8) void bp_gather18(const float* __restrict__ resT,
                                                      float* __restrict__ out) {
    __shared__ float s_acc[4 * 64];       // per-wave z-accumulator columns

    const int tid  = threadIdx.x;
    const int lane = tid & 63;            // = v
    const int wv   = tid >> 6;            // wave 0..3
    const int y    = blockIdx.x & 127;    // y-major
    const int xq   = blockIdx.x >> 7;     // 0..31
    const int xi   = xq * 4 + wv;         // 4 consecutive x per block

    const float x0 = (float)xi - 63.5f;
    const float y0 = (float)y  - 63.5f;
    const float vvf = (float)lane - 31.5f;
    const float s2  = fmaf(vvf, vvf, 262144.0f);   // vv^2 + 512^2
    const v2f vv2   = {vvf, vvf};
    const v2f one2  = {1.0f, 1.0f}, zero2 = {0.0f, 0.0f};
    const v2f h31   = {31.5f, 31.5f};
    const float cK  = -(F_L0 * INV_DL) - 1.0e-3f;

    s_acc[tid] = 0.0f;

    // per-wave rotated pair order: wave wv starts at pair 3*wv (SGPR state)
    int pj = __builtin_amdgcn_readfirstlane(3 * (tid >> 6));

    for (int j = 0; j < NA / 2; ++j) {
        const int a0 = __builtin_amdgcn_readfirstlane(2 * pj);
        const int a1 = a0 + 1;
        const float ab1a = fabsf(CSA[a0]) + fabsf(SNA[a0]);
        const float ab1b = fabsf(CSA[a1]) + fabsf(SNA[a1]);

        SETUP_ANGLE(0, a0, ab1a);         // adjacent pair: lengths nearly equal
        SETUP_ANGLE(1, a1, ab1b);

        const int trips = (max(len0, len1) + 1) & ~1;   // round up to even
        pj = (pj + 1 == NA / 2) ? 0 : pj + 1;
        if (trips == 0) continue;
        const int us0 = max(0, min(u_lo0, 128 - trips));
        const int us1 = max(0, min(u_lo1, 128 - trips));

        v2f AC00 = zero2, AC10 = zero2, AC20 = zero2;
        v2f AC01 = zero2, AC11 = zero2, AC21 = zero2;

        const float* ru0 = resT + (a0 << 13) + (us0 << 6) + lane;
        const float* ru1 = resT + (a1 << 13) + (us1 << 6) + lane;
        float uu0 = (float)us0 - 63.5f;
        float uu1 = (float)us1 - 63.5f;

        // 2-column prefetch pipeline; over-reads (<=3 cols past) stay inside ws
        float Ar0 = ru0[0],  Ar1 = ru1[0];
        float Br0 = ru0[64], Br1 = ru1[64];
#pragma unroll 1
        for (int k = 0; k < trips; k += 2) {
            const float Cr0 = ru0[128];
            const float Cr1 = ru1[128];
            const float Dr0 = ru0[192];
            const float Dr1 = ru1[192];
            BP_BODY2(0, Ar0, uu0);
            BP_BODY2(1, Ar1, uu1);
            BP_BODY2(0, Br0, uu0 + 1.0f);
            BP_BODY2(1, Br1, uu1 + 1.0f);
            Ar0 = Cr0; Ar1 = Cr1; Br0 = Dr0; Br1 = Dr1;
            ru0 += 128; ru1 += 128;
            uu0 += 2.0f; uu1 += 2.0f;
        }

        float* accw = s_acc + (wv << 6);      // wave-private column
        atomicAdd(&accw[izb0],     AC00.x + AC00.y);
        atomicAdd(&accw[izb0 + 1], AC10.x + AC10.y);
        atomicAdd(&accw[izb0 + 2], AC20.x + AC20.y);
        atomicAdd(&accw[izb1],     AC01.x + AC01.y);
        atomicAdd(&accw[izb1 + 1], AC11.x + AC11.y);
        atomicAdd(&accw[izb1 + 2], AC21.x + AC21.y);
    }
    __syncthreads();

    // writeout: 4 consecutive x per 4 lanes -> 16B chunks
    const int z  = tid >> 2;
    const int w4 = tid & 3;
    out[(z << 14) + (y << 7) + xq * 4 + w4] = s_acc[(w4 << 6) + z] * F_STEP;
}

extern "C" void kernel_launch(void* const* d_in, const int* in_sizes, int n_in,
                              void* d_out, int out_size, void* d_ws, size_t ws_size,
                              hipStream_t stream) {
    const float* x = (const float*)d_in[0];   // [1,1,64,128,128]
    const float* p = (const float*)d_in[1];   // [1,1,24,64,128]
    float* out  = (float*)d_out;              // [1,1,64,128,128]
    float* resT = (float*)d_ws;               // transposed filtered residual, NRAYS floats
    float* part = resT + NRAYS;               // 4 FP segments, 4*NRAYS floats
    float* padv = part + NSEG * NRAYS;        // padded volume, PVN floats (~4.6 MB)

    pad_kernel<<<(PVN + 255) / 256, 256, 0, stream>>>(x, padv);
    dim3 fpg(NRAYS / 256, NSEG);
    fp_seg_kernel<<<fpg, 256, 0, stream>>>(padv, part);
    ramp_kernel<<<NA * NV, NU, 0, stream>>>(part, p, resT);
    bp_gather18<<<128 * 32, 256, 0, stream>>>(resT, out);
}